// Round 3
// baseline (96.585 us; speedup 1.0000x reference)
//
#include <hip/hip_runtime.h>
#include <hip/hip_bf16.h>
#include <math.h>

typedef short bf16x8 __attribute__((ext_vector_type(8)));
typedef float f32x4 __attribute__((ext_vector_type(4)));
typedef unsigned int uint32;

#define BETA 10.0f
#define THRESH -80.0f
// Certificate: per-element bound uses exact x2/c2 and the bf16 MFMA dot.
// bf16 dot error: 20*|delta_dot| <~ 30. Skip when bound <= -80 => true arg
// <= -50 => contribution <= exp(-50)*1024*0.02 ~ 4e-20 << 1.5e-2 threshold.
// If it ever fires, the cold block recomputes everything in exact fp32.

__device__ __forceinline__ uint32 f2bf_rtne(float f) {
    uint32 u = __float_as_uint(f);
    u += 0x7FFFu + ((u >> 16) & 1u);
    return u >> 16;
}
__device__ __forceinline__ uint32 pk_rtne(float a, float b) {
    return f2bf_rtne(a) | (f2bf_rtne(b) << 16);
}
__device__ __forceinline__ uint32 pk_trunc(float a, float b) {
    return (__float_as_uint(a) >> 16) | (__float_as_uint(b) & 0xFFFF0000u);
}

#define GLDS(g, l) __builtin_amdgcn_global_load_lds( \
    (const __attribute__((address_space(1))) unsigned int*)(g), \
    (__attribute__((address_space(3))) unsigned int*)(l), 16, 0, 0)

// Prep: centers -> bf16 (RTNE), chunk-swizzled (chunk c of center j at
// j*128 + ((c+j)&7)*16) + c2m[j] = -BETA*||c_j||^2.
__global__ void rbfn_prep(const float* __restrict__ centers,
                          uint32* __restrict__ cbf,
                          float* __restrict__ c2m) {
    const int tid = threadIdx.x;
    const int j = blockIdx.x * 64 + (tid >> 2);
    const int seg = tid & 3;
    const float4* cp = (const float4*)(centers + j * 64 + seg * 16);
    const float4 f0 = cp[0], f1 = cp[1], f2 = cp[2], f3 = cp[3];
    float s = f0.x*f0.x + f0.y*f0.y + f0.z*f0.z + f0.w*f0.w
            + f1.x*f1.x + f1.y*f1.y + f1.z*f1.z + f1.w*f1.w
            + f2.x*f2.x + f2.y*f2.y + f2.z*f2.z + f2.w*f2.w
            + f3.x*f3.x + f3.y*f3.y + f3.z*f3.z + f3.w*f3.w;
    uint4 p0, p1;
    p0.x = pk_rtne(f0.x, f0.y); p0.y = pk_rtne(f0.z, f0.w);
    p0.z = pk_rtne(f1.x, f1.y); p0.w = pk_rtne(f1.z, f1.w);
    p1.x = pk_rtne(f2.x, f2.y); p1.y = pk_rtne(f2.z, f2.w);
    p1.z = pk_rtne(f3.x, f3.y); p1.w = pk_rtne(f3.z, f3.w);
    const int c0 = seg * 2, c1 = seg * 2 + 1;
    char* base = (char*)cbf + j * 128;
    *(uint4*)(base + (((c0 + j) & 7) << 4)) = p0;
    *(uint4*)(base + (((c1 + j) & 7) << 4)) = p1;
    s += __shfl_xor(s, 1);
    s += __shfl_xor(s, 2);
    if (seg == 0) c2m[j] = -BETA * s;
}

// Block = 128 rows x 512 cols (one column half). 512 thr = 8 waves:
// rowgrp (2 x 64 rows) x colgrp (4 x 128 cols). 66 KB LDS -> 2 blocks/CU.
// Hot loop is branch- and call-free: MFMA + running max bound only.
__global__ __launch_bounds__(512, 4) void rbfn_main(
    const float* __restrict__ x,
    const uint32* __restrict__ cbf,
    const float* __restrict__ c2m,
    const float* __restrict__ W,
    const float* __restrict__ bias,
    const float* __restrict__ centers,
    float* __restrict__ out)
{
    __shared__ __align__(16) char   lds_cbf[65536];
    __shared__ __align__(16) float4 scratch[4][128];  // {x2, d0, d1, d2} partials
    __shared__ __align__(16) float  lds_x2[128];
    __shared__ __align__(16) float  red[384];

    const int tid = threadIdx.x;
    const int wv = tid >> 6;
    const int lane = tid & 63;
    const int quad = lane >> 4;
    const int l15 = lane & 15;
    const int rowgrp = wv >> 2;
    const int colgrp = wv & 3;
    const int ch = blockIdx.x & 1;          // column half
    const int rb = blockIdx.x >> 1;         // row block
    const int row0 = rb * 128;
    const int col0 = ch * 512;

    // async stage this half's centers (64 KB) into LDS
    {
        const char* g = (const char*)cbf + col0 * 128 + wv * 1024 + lane * 16;
        char* l = lds_cbf + wv * 1024;
        #pragma unroll
        for (int it = 0; it < 8; ++it)
            GLDS(g + it * 8192, l + it * 8192);
    }

    // Phase 1A: x2 + fp32 x@Wx^T partials. thread = (row r, quarter q);
    // q is wave-uniform -> W loads scalarize.
    {
        const int r = tid & 127, q = tid >> 7;
        const float4* px = (const float4*)(x + (size_t)(row0 + r) * 64) + q * 4;
        const float4 v0 = px[0], v1 = px[1], v2 = px[2], v3 = px[3];
        const float4* w0p = (const float4*)(W + 0 * 1088 + q * 16);
        const float4* w1p = (const float4*)(W + 1 * 1088 + q * 16);
        const float4* w2p = (const float4*)(W + 2 * 1088 + q * 16);
        float s2 = v0.x*v0.x + v0.y*v0.y + v0.z*v0.z + v0.w*v0.w
                 + v1.x*v1.x + v1.y*v1.y + v1.z*v1.z + v1.w*v1.w
                 + v2.x*v2.x + v2.y*v2.y + v2.z*v2.z + v2.w*v2.w
                 + v3.x*v3.x + v3.y*v3.y + v3.z*v3.z + v3.w*v3.w;
        float d0 = 0.f, d1 = 0.f, d2 = 0.f;
        const float4 vv[4] = {v0, v1, v2, v3};
        #pragma unroll
        for (int i = 0; i < 4; ++i) {
            const float4 a = vv[i], b0 = w0p[i], b1 = w1p[i], b2 = w2p[i];
            d0 += a.x*b0.x + a.y*b0.y + a.z*b0.z + a.w*b0.w;
            d1 += a.x*b1.x + a.y*b1.y + a.z*b1.z + a.w*b1.w;
            d2 += a.x*b2.x + a.y*b2.y + a.z*b2.z + a.w*b2.w;
        }
        float4 o; o.x = s2; o.y = d0; o.z = d1; o.w = d2;
        scratch[q][r] = o;
    }

    // Phase 2: A fragments (trunc bf16) while scratch settles
    bf16x8 af[4][2];
    #pragma unroll
    for (int rt = 0; rt < 4; ++rt) {
        const float4* px = (const float4*)(x + (size_t)(row0 + rowgrp * 64 + rt * 16 + l15) * 64) + quad * 2;
        #pragma unroll
        for (int kk = 0; kk < 2; ++kk) {
            const float4 u0 = px[kk * 8];
            const float4 u1 = px[kk * 8 + 1];
            union { bf16x8 v; uint4 u; } t;
            t.u.x = pk_trunc(u0.x, u0.y);
            t.u.y = pk_trunc(u0.z, u0.w);
            t.u.z = pk_trunc(u1.x, u1.y);
            t.u.w = pk_trunc(u1.z, u1.w);
            af[rt][kk] = t.v;
        }
    }

    // Phase 3: column constants
    float c2r[8];
    #pragma unroll
    for (int ct = 0; ct < 8; ++ct)
        c2r[ct] = c2m[col0 + colgrp * 128 + ct * 16 + l15];

    __syncthreads();

    // Phase 1B: combine quarters -> lds_x2 + seeded red
    if (tid < 128) {
        const float4 a = scratch[0][tid], b = scratch[1][tid];
        const float4 c = scratch[2][tid], d = scratch[3][tid];
        lds_x2[tid] = a.x + b.x + c.x + d.x;
        const float z = (ch == 0) ? 1.f : 0.f;
        red[tid * 3 + 0] = (a.y + b.y + c.y + d.y + bias[0]) * z;
        red[tid * 3 + 1] = (a.z + b.z + c.z + d.z + bias[1]) * z;
        red[tid * 3 + 2] = (a.w + b.w + c.w + d.w + bias[2]) * z;
    }
    __syncthreads();

    // Phase 4: per-lane row constants -BETA*||x_row||^2
    float prer[16];
    #pragma unroll
    for (int rt = 0; rt < 4; ++rt) {
        const float4 q4 = *(const float4*)&lds_x2[rowgrp * 64 + rt * 16 + quad * 4];
        prer[rt * 4 + 0] = -BETA * q4.x;
        prer[rt * 4 + 1] = -BETA * q4.y;
        prer[rt * 4 + 2] = -BETA * q4.z;
        prer[rt * 4 + 3] = -BETA * q4.w;
    }

    // Phase 5: hot loop — 8 col-tiles, branch-free, certificate max only
    const char* cb = lds_cbf;
    const int jl = colgrp * 128 + l15;
    const int base0 = jl * 128 + (((quad + jl) & 7) << 4);
    const int base1 = jl * 128 + (((quad + 4 + jl) & 7) << 4);
    bf16x8 b0 = *(const bf16x8*)(cb + base0);
    bf16x8 b1 = *(const bf16x8*)(cb + base1);
    float gmax = -1e30f;
    #pragma unroll
    for (int ct = 0; ct < 8; ++ct) {
        bf16x8 nb0 = b0, nb1 = b1;
        if (ct < 7) {
            nb0 = *(const bf16x8*)(cb + base0 + (ct + 1) * 2048);
            nb1 = *(const bf16x8*)(cb + base1 + (ct + 1) * 2048);
        }
        f32x4 acc[4];
        #pragma unroll
        for (int rt = 0; rt < 4; ++rt) {
            const f32x4 z = {0.f, 0.f, 0.f, 0.f};
            acc[rt] = __builtin_amdgcn_mfma_f32_16x16x32_bf16(af[rt][0], b0, z, 0, 0, 0);
            acc[rt] = __builtin_amdgcn_mfma_f32_16x16x32_bf16(af[rt][1], b1, acc[rt], 0, 0, 0);
        }
        float m = -1e30f;
        #pragma unroll
        for (int rt = 0; rt < 4; ++rt)
            #pragma unroll
            for (int rg = 0; rg < 4; ++rg)
                m = fmaxf(m, fmaf(acc[rt][rg], 2.0f * BETA, prer[rt * 4 + rg]));
        gmax = fmaxf(gmax, m + c2r[ct]);
        b0 = nb0; b1 = nb1;
    }

    // Phase 6: cold exact path (never taken with this data; inline, no call)
    if (__builtin_expect(__ballot(gmax > THRESH) != 0ull, 0)) {
        #pragma clang loop unroll(disable)
        for (int ct = 0; ct < 8; ++ct) {
            const int j = col0 + colgrp * 128 + ct * 16 + l15;
            #pragma clang loop unroll(disable)
            for (int rr = 0; rr < 16; ++rr) {
                const int r = rowgrp * 64 + (rr >> 2) * 16 + quad * 4 + (rr & 3);
                const float* xr = x + (size_t)(row0 + r) * 64;
                const float* cr = centers + (size_t)j * 64;
                float d2 = 0.f;
                #pragma clang loop unroll(disable)
                for (int k = 0; k < 64; ++k) {
                    const float df = xr[k] - cr[k];
                    d2 = fmaf(df, df, d2);
                }
                const float arg = -BETA * d2;
                if (arg > -87.f) {
                    const float e = expf(arg);
                    atomicAdd(&red[r * 3 + 0], e * W[0 * 1088 + 64 + j]);
                    atomicAdd(&red[r * 3 + 1], e * W[1 * 1088 + 64 + j]);
                    atomicAdd(&red[r * 3 + 2], e * W[2 * 1088 + 64 + j]);
                }
            }
        }
    }
    __syncthreads();

    // Phase 7: combine the two column halves via global fp32 atomics
    if (tid < 384)
        atomicAdd(out + (size_t)row0 * 3 + tid, red[tid]);
}

extern "C" void kernel_launch(void* const* d_in, const int* in_sizes, int n_in,
                              void* d_out, int out_size, void* d_ws, size_t ws_size,
                              hipStream_t stream) {
    const float* x       = (const float*)d_in[0];
    const float* centers = (const float*)d_in[1];
    const float* W       = (const float*)d_in[2];
    const float* b       = (const float*)d_in[3];
    float* out = (float*)d_out;

    float*  c2m = (float*)d_ws;                         // 4 KB
    uint32* cbf = (uint32*)((char*)d_ws + 4096);        // 128 KB swizzled bf16

    const int n = in_sizes[0] / 64;                     // 65536

    hipMemsetAsync(d_out, 0, (size_t)out_size * sizeof(float), stream);
    rbfn_prep<<<16, 256, 0, stream>>>(centers, cbf, c2m);
    rbfn_main<<<(n / 128) * 2, 512, 0, stream>>>(x, cbf, c2m, W, b, centers, out);
}

// Round 4
// 88.360 us; speedup vs baseline: 1.0931x; 1.0931x over previous
//
#include <hip/hip_runtime.h>
#include <math.h>

typedef short bf16x8 __attribute__((ext_vector_type(8)));
typedef float f32x4 __attribute__((ext_vector_type(4)));
typedef unsigned int uint32;

#define BETA 10.0f
#define THRESH -80.0f
// Certificate: bound = max_ct(20*max_rows(acc) + c2_ct) + max_rows(-10*||x||^2)
// >= true max arg (valid upper bound; max decomposition). Both A and B are
// trunc-rounded bf16: |dot err| <= ~0.4 -> 20*err <= 8. Not fired => every
// true arg <= -72 => contribution <= exp(-72)*1024*0.02 ~ 1e-29 << 1.5e-2.
// If fired (P ~ 1e-2 over the whole problem), cold path recomputes exact fp32.

__device__ __forceinline__ uint32 pk_trunc(float a, float b) {
    return (__float_as_uint(a) >> 16) | (__float_as_uint(b) & 0xFFFF0000u);
}
__device__ __forceinline__ f32x4 vmax4(f32x4 a, f32x4 b) {
    f32x4 r;
    r[0] = fmaxf(a[0], b[0]); r[1] = fmaxf(a[1], b[1]);
    r[2] = fmaxf(a[2], b[2]); r[3] = fmaxf(a[3], b[3]);
    return r;
}

// Single fused kernel. Block = 256 rows x 1024 centers, 1024 thr = 16 waves
// (4/SIMD): wave = rowgrp (4 x 64 rows) x colgrp (4 x 256 cols).
// LDS 152 KB -> 1 block/CU by design; grid 256 = one block per CU.
// Centers are converted to bf16 in-block (L2-resident, overlaps the x read).
// LDS B layout: chunk c (= k/8) of center j at (j>>4)*2048 + c*256 + (j&15)*16
// -> hot-loop ds_read_b128 is a contiguous 256B stripe per quad (2-way, free).
__global__ __launch_bounds__(1024, 4) void rbfn_fused(
    const float* __restrict__ x,
    const float* __restrict__ centers,
    const float* __restrict__ W,
    const float* __restrict__ bias,
    float* __restrict__ out)
{
    __shared__ __align__(16) char   lds_cbf[131072];
    __shared__ __align__(16) float  lds_c2[1024];
    __shared__ __align__(16) float4 scratch[4][256];
    __shared__ __align__(16) float  lds_x2[256];
    __shared__ __align__(16) float  red[768];

    const int tid = threadIdx.x;
    const int wv = tid >> 6;
    const int lane = tid & 63;
    const int quad = lane >> 4;
    const int l15 = lane & 15;
    const int rowgrp = wv >> 2;
    const int colgrp = wv & 3;
    const int row0 = blockIdx.x * 256;

    // ---- centers -> bf16 LDS (thread j = tid owns center j) + c2 ----
    {
        const float4* cj = (const float4*)(centers + tid * 64);
        char* dst = lds_cbf + ((tid >> 4) * 2048 + (tid & 15) * 16);
        float s = 0.f;
        #pragma unroll
        for (int c = 0; c < 8; ++c) {
            const float4 f0 = cj[c * 2], f1 = cj[c * 2 + 1];
            s += f0.x*f0.x + f0.y*f0.y + f0.z*f0.z + f0.w*f0.w
               + f1.x*f1.x + f1.y*f1.y + f1.z*f1.z + f1.w*f1.w;
            uint4 p;
            p.x = pk_trunc(f0.x, f0.y); p.y = pk_trunc(f0.z, f0.w);
            p.z = pk_trunc(f1.x, f1.y); p.w = pk_trunc(f1.z, f1.w);
            *(uint4*)(dst + c * 256) = p;
        }
        lds_c2[tid] = -BETA * s;
    }

    // ---- phase 1: ||x||^2 + exact fp32 x@Wx^T partials ----
    // wave handles its own 64 MFMA rows; quarter q = colgrp (wave-uniform ->
    // W reads scalarize to s_load).
    {
        const int q = __builtin_amdgcn_readfirstlane(colgrp);
        const int r = rowgrp * 64 + lane;
        const float4* px = (const float4*)(x + (size_t)(row0 + r) * 64 + q * 16);
        const float4 v0 = px[0], v1 = px[1], v2 = px[2], v3 = px[3];
        const float* w0 = W + 0 * 1088 + q * 16;
        const float* w1 = W + 1 * 1088 + q * 16;
        const float* w2 = W + 2 * 1088 + q * 16;
        const float4 vv[4] = {v0, v1, v2, v3};
        float s2 = 0.f, d0 = 0.f, d1 = 0.f, d2 = 0.f;
        #pragma unroll
        for (int i = 0; i < 4; ++i) {
            const float4 a = vv[i];
            s2 += a.x*a.x + a.y*a.y + a.z*a.z + a.w*a.w;
            d0 = fmaf(a.w, w0[i*4+3], fmaf(a.z, w0[i*4+2], fmaf(a.y, w0[i*4+1], fmaf(a.x, w0[i*4+0], d0))));
            d1 = fmaf(a.w, w1[i*4+3], fmaf(a.z, w1[i*4+2], fmaf(a.y, w1[i*4+1], fmaf(a.x, w1[i*4+0], d1))));
            d2 = fmaf(a.w, w2[i*4+3], fmaf(a.z, w2[i*4+2], fmaf(a.y, w2[i*4+1], fmaf(a.x, w2[i*4+0], d2))));
        }
        float4 o; o.x = s2; o.y = d0; o.z = d1; o.w = d2;
        scratch[q][r] = o;
    }

    // ---- A fragments (trunc bf16; global x only, no LDS dependency) ----
    bf16x8 af[4][2];
    #pragma unroll
    for (int rt = 0; rt < 4; ++rt) {
        const float4* px = (const float4*)(x + (size_t)(row0 + rowgrp * 64 + rt * 16 + l15) * 64) + quad * 2;
        #pragma unroll
        for (int kk = 0; kk < 2; ++kk) {
            const float4 u0 = px[kk * 8];
            const float4 u1 = px[kk * 8 + 1];
            union { bf16x8 v; uint4 u; } t;
            t.u.x = pk_trunc(u0.x, u0.y);
            t.u.y = pk_trunc(u0.z, u0.w);
            t.u.z = pk_trunc(u1.x, u1.y);
            t.u.w = pk_trunc(u1.z, u1.w);
            af[rt][kk] = t.v;
        }
    }

    __syncthreads();

    // ---- combine quarters -> x2 + seeded red (dot + bias) ----
    if (tid < 256) {
        const float4 a = scratch[0][tid], b = scratch[1][tid];
        const float4 c = scratch[2][tid], d = scratch[3][tid];
        lds_x2[tid] = a.x + b.x + c.x + d.x;
        red[tid * 3 + 0] = a.y + b.y + c.y + d.y + bias[0];
        red[tid * 3 + 1] = a.z + b.z + c.z + d.z + bias[1];
        red[tid * 3 + 2] = a.w + b.w + c.w + d.w + bias[2];
    }
    __syncthreads();

    // ---- per-lane prermax = max over this lane's 16 acc rows of -B*||x||^2
    float mn = 1e30f;
    #pragma unroll
    for (int rt = 0; rt < 4; ++rt) {
        const float4 q4 = *(const float4*)&lds_x2[rowgrp * 64 + rt * 16 + quad * 4];
        mn = fminf(mn, fminf(fminf(q4.x, q4.y), fminf(q4.z, q4.w)));
    }
    const float prermax = -BETA * mn;

    // ---- hot loop: 16 col-tiles, branch-free, MFMA + max fold only ----
    const char* cb = lds_cbf + colgrp * 32768 + quad * 256 + l15 * 16;
    bf16x8 b0 = *(const bf16x8*)(cb);
    bf16x8 b1 = *(const bf16x8*)(cb + 1024);
    float gm = -1e30f;
    #pragma unroll
    for (int ct = 0; ct < 16; ++ct) {
        bf16x8 nb0 = b0, nb1 = b1;
        if (ct < 15) {
            nb0 = *(const bf16x8*)(cb + (ct + 1) * 2048);
            nb1 = *(const bf16x8*)(cb + (ct + 1) * 2048 + 1024);
        }
        const float c2v = lds_c2[colgrp * 256 + ct * 16 + l15];
        f32x4 acc[4];
        #pragma unroll
        for (int rt = 0; rt < 4; ++rt) {
            const f32x4 z = {0.f, 0.f, 0.f, 0.f};
            acc[rt] = __builtin_amdgcn_mfma_f32_16x16x32_bf16(af[rt][0], b0, z, 0, 0, 0);
            acc[rt] = __builtin_amdgcn_mfma_f32_16x16x32_bf16(af[rt][1], b1, acc[rt], 0, 0, 0);
        }
        f32x4 m0 = vmax4(vmax4(acc[0], acc[1]), vmax4(acc[2], acc[3]));
        const float m = fmaxf(fmaxf(m0[0], m0[1]), fmaxf(m0[2], m0[3]));
        gm = fmaxf(gm, fmaf(2.0f * BETA, m, c2v));
        b0 = nb0; b1 = nb1;
    }
    const float bound = gm + prermax;

    // ---- cold exact path (statistically never; conservative fallback) ----
    if (__builtin_expect(__ballot(bound > THRESH) != 0ull, 0)) {
        #pragma clang loop unroll(disable)
        for (int ct = 0; ct < 16; ++ct) {
            const int j = colgrp * 256 + ct * 16 + l15;
            #pragma clang loop unroll(disable)
            for (int rr = 0; rr < 16; ++rr) {
                const int r = rowgrp * 64 + (rr >> 2) * 16 + quad * 4 + (rr & 3);
                const float* xr = x + (size_t)(row0 + r) * 64;
                const float* cr = centers + (size_t)j * 64;
                float d2 = 0.f;
                #pragma clang loop unroll(disable)
                for (int k = 0; k < 64; ++k) {
                    const float df = xr[k] - cr[k];
                    d2 = fmaf(df, df, d2);
                }
                const float arg = -BETA * d2;
                if (arg > -87.f) {
                    const float e = expf(arg);
                    atomicAdd(&red[r * 3 + 0], e * W[0 * 1088 + 64 + j]);
                    atomicAdd(&red[r * 3 + 1], e * W[1 * 1088 + 64 + j]);
                    atomicAdd(&red[r * 3 + 2], e * W[2 * 1088 + 64 + j]);
                }
            }
        }
    }
    __syncthreads();

    // ---- epilogue: deterministic coalesced store ----
    if (tid < 192)
        ((float4*)out)[blockIdx.x * 192 + tid] = *((const float4*)red + tid);
}

extern "C" void kernel_launch(void* const* d_in, const int* in_sizes, int n_in,
                              void* d_out, int out_size, void* d_ws, size_t ws_size,
                              hipStream_t stream) {
    const float* x       = (const float*)d_in[0];
    const float* centers = (const float*)d_in[1];
    const float* W       = (const float*)d_in[2];
    const float* b       = (const float*)d_in[3];
    float* out = (float*)d_out;

    const int n = in_sizes[0] / 64;   // 65536 rows
    rbfn_fused<<<n / 256, 1024, 0, stream>>>(x, centers, W, b, out);
}

// Round 5
// 80.094 us; speedup vs baseline: 1.2059x; 1.1032x over previous
//
#include <hip/hip_runtime.h>
#include <math.h>

typedef short bf16x8 __attribute__((ext_vector_type(8)));
typedef float f32x4 __attribute__((ext_vector_type(4)));
typedef unsigned int uint32;

#define BETA 10.0f
#define THRESH -80.0f
// Certificate: bound = max_ct(20*max_allrows(acc) + c2_ct) + max_rows(-10*||x||^2)
// >= true max arg. A,B both RTNE bf16 -> 20*|dot err| <= ~4; x2 from bf16 adds
// <= ~3. Not fired => every true arg <= -73 => contribution <= exp(-73)*1024*0.02
// ~ 4e-30 << 1.5e-2. If fired, cold path recomputes exact fp32 from x/centers.

// LDS map (single array; GLDS region must be linear & contiguous)
#define C_OFF   0         // 131072 B: centers bf16, chunk layout
#define C2_OFF  131072    // 4096 B: -BETA*||c_j||^2 fp32
#define XB_OFF  135168    // 16384 B: x bf16, chunk layout (128 rows)
#define W_OFF   151552    // 768 B: W_x fp32 [3][64]
#define X2_OFF  152320    // 512 B: ||x_r||^2
#define RED_OFF 152832    // 1536 B: out accumulator [128][3]
#define LDS_TOT 154368

__device__ __forceinline__ uint32 f2bf_rtne(float f) {
    uint32 u = __float_as_uint(f);
    u += 0x7FFFu + ((u >> 16) & 1u);
    return u >> 16;
}
__device__ __forceinline__ uint32 pk_rtne(float a, float b) {
    return f2bf_rtne(a) | (f2bf_rtne(b) << 16);
}
__device__ __forceinline__ float bf2f(short s) {
    return __uint_as_float(((uint32)(unsigned short)s) << 16);
}
__device__ __forceinline__ f32x4 vmax4(f32x4 a, f32x4 b) {
    f32x4 r;
    r[0] = fmaxf(a[0], b[0]); r[1] = fmaxf(a[1], b[1]);
    r[2] = fmaxf(a[2], b[2]); r[3] = fmaxf(a[3], b[3]);
    return r;
}

#define GLDS(g, l) __builtin_amdgcn_global_load_lds( \
    (const __attribute__((address_space(1))) unsigned int*)(g), \
    (__attribute__((address_space(3))) unsigned int*)(l), 16, 0, 0)

// Prep: centers -> bf16 RTNE in chunk layout (16-B chunk c of center j at
// (j>>4)*2048 + c*256 + (j&15)*16) + c2m[j] = -BETA*||c_j||^2 (exact fp32).
__global__ void rbfn_prep(const float* __restrict__ centers,
                          uint32* __restrict__ cbf,
                          float* __restrict__ c2m) {
    const int tid = threadIdx.x;
    const int j = blockIdx.x * 64 + (tid >> 2);
    const int seg = tid & 3;                      // 16-float segment
    const float4* cp = (const float4*)(centers + j * 64 + seg * 16);
    const float4 f0 = cp[0], f1 = cp[1], f2 = cp[2], f3 = cp[3];
    float s = f0.x*f0.x + f0.y*f0.y + f0.z*f0.z + f0.w*f0.w
            + f1.x*f1.x + f1.y*f1.y + f1.z*f1.z + f1.w*f1.w
            + f2.x*f2.x + f2.y*f2.y + f2.z*f2.z + f2.w*f2.w
            + f3.x*f3.x + f3.y*f3.y + f3.z*f3.z + f3.w*f3.w;
    uint4 p0, p1;
    p0.x = pk_rtne(f0.x, f0.y); p0.y = pk_rtne(f0.z, f0.w);
    p0.z = pk_rtne(f1.x, f1.y); p0.w = pk_rtne(f1.z, f1.w);
    p1.x = pk_rtne(f2.x, f2.y); p1.y = pk_rtne(f2.z, f2.w);
    p1.z = pk_rtne(f3.x, f3.y); p1.w = pk_rtne(f3.z, f3.w);
    char* base = (char*)cbf + (j >> 4) * 2048 + (j & 15) * 16;
    *(uint4*)(base + (seg * 2 + 0) * 256) = p0;
    *(uint4*)(base + (seg * 2 + 1) * 256) = p1;
    s += __shfl_xor(s, 1);
    s += __shfl_xor(s, 2);
    if (seg == 0) c2m[j] = -BETA * s;
}

// Main: block = 128 rows x 1024 centers; 512 thr = 8 waves, wave = colgrp
// (128 cols), each wave covers ALL 128 rows (af[8][2], 16 MFMA per B-pair).
// All global reads coalesced; LDS does every transpose. 150.75 KB -> 1 blk/CU.
__global__ __launch_bounds__(512, 2) void rbfn_main(
    const float* __restrict__ x,
    const char* __restrict__ ws,      // [cbf 128K][c2m 4K] linear
    const float* __restrict__ W,
    const float* __restrict__ bias,
    const float* __restrict__ centers,
    float* __restrict__ out)
{
    __shared__ __align__(16) char lds[LDS_TOT];

    const int tid = threadIdx.x;
    const int wv = tid >> 6;
    const int lane = tid & 63;
    const int quad = lane >> 4;
    const int l15 = lane & 15;
    const int row0 = blockIdx.x * 128;

    const float bb0 = bias[0], bb1 = bias[1], bb2 = bias[2];

    // ---- coalesced async stage: centers bf16 + c2 (132 KB linear) ----
    {
        const char* g = ws + wv * 1024 + lane * 16;
        char* l = lds + wv * 1024;
        #pragma unroll
        for (int it = 0; it < 16; ++it)
            GLDS(g + it * 8192, l + it * 8192);
        if (wv < 4)
            GLDS(ws + 131072 + wv * 1024 + lane * 16, lds + 131072 + wv * 1024);
    }

    // ---- coalesced x read -> RTNE bf16 -> LDS chunk layout ----
    {
        const float4* xg = (const float4*)(x + (size_t)row0 * 64);
        #pragma unroll
        for (int i = 0; i < 4; ++i) {
            const int f = tid + 512 * i;          // float4 index in tile
            const float4 v = xg[f];
            const int row = f >> 4, sg = f & 15;
            uint2 q;
            q.x = pk_rtne(v.x, v.y);
            q.y = pk_rtne(v.z, v.w);
            *(uint2*)(lds + XB_OFF + (row >> 4) * 2048 + (sg >> 1) * 256 +
                      (row & 15) * 16 + (sg & 1) * 8) = q;
        }
    }
    // ---- W_x (3x64 fp32, 768 B) -> LDS ----
    if (tid < 48) {
        const int k = tid >> 4, c = tid & 15;
        *((float4*)(lds + W_OFF) + tid) = *((const float4*)(W + k * 1088) + c);
    }

    __syncthreads();   // GLDS + x/W staging complete

    // ---- A fragments from LDS (contiguous-1KB reads, bank floor) ----
    bf16x8 af[8][2];
    #pragma unroll
    for (int rt = 0; rt < 8; ++rt) {
        const char* ab = lds + XB_OFF + rt * 2048 + l15 * 16;
        af[rt][0] = *(const bf16x8*)(ab + quad * 256);
        af[rt][1] = *(const bf16x8*)(ab + (4 + quad) * 256);
    }

    // ---- x2 + Wx-dots from bf16 LDS tile: thread = (row, quarter) ----
    {
        const int r = tid >> 2, qq = tid & 3;
        const char* xr = lds + XB_OFF + (r >> 4) * 2048 + (r & 15) * 16;
        const bf16x8 h0 = *(const bf16x8*)(xr + (qq * 2 + 0) * 256);
        const bf16x8 h1 = *(const bf16x8*)(xr + (qq * 2 + 1) * 256);
        const float* w0 = (const float*)(lds + W_OFF) + 0 * 64 + qq * 16;
        const float* w1 = (const float*)(lds + W_OFF) + 1 * 64 + qq * 16;
        const float* w2 = (const float*)(lds + W_OFF) + 2 * 64 + qq * 16;
        float s2 = 0.f, d0 = 0.f, d1 = 0.f, d2 = 0.f;
        #pragma unroll
        for (int e = 0; e < 8; ++e) {
            const float a = bf2f(h0[e]), b = bf2f(h1[e]);
            s2 = fmaf(a, a, s2); s2 = fmaf(b, b, s2);
            d0 = fmaf(a, w0[e], d0); d0 = fmaf(b, w0[8 + e], d0);
            d1 = fmaf(a, w1[e], d1); d1 = fmaf(b, w1[8 + e], d1);
            d2 = fmaf(a, w2[e], d2); d2 = fmaf(b, w2[8 + e], d2);
        }
        #pragma unroll
        for (int m = 1; m <= 2; m <<= 1) {
            s2 += __shfl_xor(s2, m);
            d0 += __shfl_xor(d0, m);
            d1 += __shfl_xor(d1, m);
            d2 += __shfl_xor(d2, m);
        }
        if (qq == 0) {
            ((float*)(lds + X2_OFF))[r] = s2;
            float* red = (float*)(lds + RED_OFF);
            red[r * 3 + 0] = d0 + bb0;
            red[r * 3 + 1] = d1 + bb1;
            red[r * 3 + 2] = d2 + bb2;
        }
    }
    __syncthreads();   // x2 / red seeded

    // ---- prermax = -BETA * min over this lane's 32 output rows of ||x||^2
    const float* px2 = (const float*)(lds + X2_OFF);
    float mn = 1e30f;
    #pragma unroll
    for (int rt = 0; rt < 8; ++rt) {
        const float4 q4 = *(const float4*)(px2 + rt * 16 + quad * 4);
        mn = fminf(mn, fminf(fminf(q4.x, q4.y), fminf(q4.z, q4.w)));
    }
    const float prermax = -BETA * mn;

    // ---- hot loop: 8 col-tiles/wave, branch-free, 16 MFMA per B-pair ----
    const char* cB = lds + wv * 16384 + quad * 256 + l15 * 16;
    const float* c2p = (const float*)(lds + C2_OFF) + wv * 128 + l15;
    float gm = -1e30f;
    #pragma unroll
    for (int ct = 0; ct < 8; ++ct) {
        const bf16x8 b0 = *(const bf16x8*)(cB + ct * 2048);
        const bf16x8 b1 = *(const bf16x8*)(cB + ct * 2048 + 1024);
        const float c2v = c2p[ct * 16];
        f32x4 acc[8];
        #pragma unroll
        for (int rt = 0; rt < 8; ++rt) {
            const f32x4 z = {0.f, 0.f, 0.f, 0.f};
            acc[rt] = __builtin_amdgcn_mfma_f32_16x16x32_bf16(af[rt][0], b0, z, 0, 0, 0);
            acc[rt] = __builtin_amdgcn_mfma_f32_16x16x32_bf16(af[rt][1], b1, acc[rt], 0, 0, 0);
        }
        f32x4 m0 = vmax4(vmax4(acc[0], acc[1]), vmax4(acc[2], acc[3]));
        f32x4 m1 = vmax4(vmax4(acc[4], acc[5]), vmax4(acc[6], acc[7]));
        m0 = vmax4(m0, m1);
        const float m = fmaxf(fmaxf(m0[0], m0[1]), fmaxf(m0[2], m0[3]));
        gm = fmaxf(gm, fmaf(2.0f * BETA, m, c2v));
    }
    const float bound = gm + prermax;

    // ---- cold exact path (statistically never; conservative fallback) ----
    if (__builtin_expect(__ballot(bound > THRESH) != 0ull, 0)) {
        float* red = (float*)(lds + RED_OFF);
        #pragma clang loop unroll(disable)
        for (int ct = 0; ct < 8; ++ct) {
            const int j = wv * 128 + ct * 16 + l15;
            #pragma clang loop unroll(disable)
            for (int rr = 0; rr < 32; ++rr) {
                const int r = (rr >> 2) * 16 + quad * 4 + (rr & 3);
                const float* xr = x + (size_t)(row0 + r) * 64;
                const float* cr = centers + (size_t)j * 64;
                float d2 = 0.f;
                #pragma clang loop unroll(disable)
                for (int k = 0; k < 64; ++k) {
                    const float df = xr[k] - cr[k];
                    d2 = fmaf(df, df, d2);
                }
                const float arg = -BETA * d2;
                if (arg > -87.f) {
                    const float e = expf(arg);
                    atomicAdd(&red[r * 3 + 0], e * W[0 * 1088 + 64 + j]);
                    atomicAdd(&red[r * 3 + 1], e * W[1 * 1088 + 64 + j]);
                    atomicAdd(&red[r * 3 + 2], e * W[2 * 1088 + 64 + j]);
                }
            }
        }
    }
    __syncthreads();

    // ---- epilogue: coalesced float4 store (bias already folded) ----
    if (tid < 96)
        ((float4*)out)[blockIdx.x * 96 + tid] = *((const float4*)(lds + RED_OFF) + tid);
}

extern "C" void kernel_launch(void* const* d_in, const int* in_sizes, int n_in,
                              void* d_out, int out_size, void* d_ws, size_t ws_size,
                              hipStream_t stream) {
    const float* x       = (const float*)d_in[0];
    const float* centers = (const float*)d_in[1];
    const float* W       = (const float*)d_in[2];
    const float* b       = (const float*)d_in[3];
    float* out = (float*)d_out;

    uint32* cbf = (uint32*)d_ws;                        // 128 KB bf16 chunks
    float*  c2m = (float*)((char*)d_ws + 131072);       // 4 KB -B*||c||^2

    const int n = in_sizes[0] / 64;                     // 65536 rows

    rbfn_prep<<<16, 256, 0, stream>>>(centers, cbf, c2m);
    rbfn_main<<<n / 128, 512, 0, stream>>>(x, (const char*)d_ws, W, b, centers, out);
}

// Round 6
// 79.322 us; speedup vs baseline: 1.2176x; 1.0097x over previous
//
#include <hip/hip_runtime.h>
#include <math.h>

typedef short bf16x8 __attribute__((ext_vector_type(8)));
typedef float f32x4 __attribute__((ext_vector_type(4)));
typedef unsigned int uint32;

#define BETA 10.0f
#define THRESH -80.0f
// Certificate: bound = max_ct(20*max_allrows(acc) + c2_ct) + max_rows(-10*||x||^2)
// >= true max arg. A,B RTNE bf16 -> 20*|dot err| <= ~4; bf16 x2 adds <= ~3.
// Not fired => true arg <= -73 => contribution <= exp(-73)*1024*0.02 ~ 4e-30
// << 1.5e-2. If fired, cold path recomputes exact fp32 from x/centers.

// LDS map (GLDS region [C_OFF..C2_OFF+4K) is linear & contiguous)
#define C_OFF    0         // 131072 B: centers bf16, chunk layout
#define C2_OFF   131072    // 4096 B: -BETA*||c_j||^2 fp32
#define XB_OFF   135168    // 16384 B: x bf16 chunk layout (one 128-row tile)
#define W_OFF    151552    // 768 B: W_x fp32 [3][64]
#define X2_OFF   152320    // 512 B: ||x_r||^2 (current tile)
#define RED_OFF  152832    // 2x1536 B: out accumulators [tile][128][3]
#define LDS_TOT  155904    // 152.25 KB -> 1 block/CU

__device__ __forceinline__ uint32 f2bf_rtne(float f) {
    uint32 u = __float_as_uint(f);
    u += 0x7FFFu + ((u >> 16) & 1u);
    return u >> 16;
}
__device__ __forceinline__ uint32 pk_rtne(float a, float b) {
    return f2bf_rtne(a) | (f2bf_rtne(b) << 16);
}
__device__ __forceinline__ float bf2f(short s) {
    return __uint_as_float(((uint32)(unsigned short)s) << 16);
}
__device__ __forceinline__ f32x4 vmax4(f32x4 a, f32x4 b) {
    f32x4 r;
    r[0] = fmaxf(a[0], b[0]); r[1] = fmaxf(a[1], b[1]);
    r[2] = fmaxf(a[2], b[2]); r[3] = fmaxf(a[3], b[3]);
    return r;
}

#define GLDS(g, l) __builtin_amdgcn_global_load_lds( \
    (const __attribute__((address_space(1))) unsigned int*)(g), \
    (__attribute__((address_space(3))) unsigned int*)(l), 16, 0, 0)

// Prep: centers -> bf16 RTNE chunk layout + c2m[j] = -BETA*||c_j||^2.
__global__ void rbfn_prep(const float* __restrict__ centers,
                          uint32* __restrict__ cbf,
                          float* __restrict__ c2m) {
    const int tid = threadIdx.x;
    const int j = blockIdx.x * 64 + (tid >> 2);
    const int seg = tid & 3;
    const float4* cp = (const float4*)(centers + j * 64 + seg * 16);
    const float4 f0 = cp[0], f1 = cp[1], f2 = cp[2], f3 = cp[3];
    float s = f0.x*f0.x + f0.y*f0.y + f0.z*f0.z + f0.w*f0.w
            + f1.x*f1.x + f1.y*f1.y + f1.z*f1.z + f1.w*f1.w
            + f2.x*f2.x + f2.y*f2.y + f2.z*f2.z + f2.w*f2.w
            + f3.x*f3.x + f3.y*f3.y + f3.z*f3.z + f3.w*f3.w;
    uint4 p0, p1;
    p0.x = pk_rtne(f0.x, f0.y); p0.y = pk_rtne(f0.z, f0.w);
    p0.z = pk_rtne(f1.x, f1.y); p0.w = pk_rtne(f1.z, f1.w);
    p1.x = pk_rtne(f2.x, f2.y); p1.y = pk_rtne(f2.z, f2.w);
    p1.z = pk_rtne(f3.x, f3.y); p1.w = pk_rtne(f3.z, f3.w);
    char* base = (char*)cbf + (j >> 4) * 2048 + (j & 15) * 16;
    *(uint4*)(base + (seg * 2 + 0) * 256) = p0;
    *(uint4*)(base + (seg * 2 + 1) * 256) = p1;
    s += __shfl_xor(s, 1);
    s += __shfl_xor(s, 2);
    if (seg == 0) c2m[j] = -BETA * s;
}

// Main: persistent block = 256 rows (2 tiles of 128) x 1024 centers.
// Grid 256 = 1 block/CU; centers staged ONCE per CU. 512 thr = 8 waves,
// wave = 128-col group covering all 128 rows of the current tile.
__global__ __launch_bounds__(512, 2) void rbfn_main(
    const float* __restrict__ x,
    const char* __restrict__ ws,      // [cbf 128K][c2m 4K] linear
    const float* __restrict__ W,
    const float* __restrict__ bias,
    const float* __restrict__ centers,
    float* __restrict__ out)
{
    __shared__ __align__(16) char lds[LDS_TOT];

    const int tid = threadIdx.x;
    const int wv = tid >> 6;
    const int lane = tid & 63;
    const int quad = lane >> 4;
    const int l15 = lane & 15;
    const int row0 = blockIdx.x * 256;

    const float bb0 = bias[0], bb1 = bias[1], bb2 = bias[2];

    // ---- coalesced async stage: centers bf16 + c2 (132 KB linear), once ----
    {
        const char* g = ws + wv * 1024 + lane * 16;
        char* l = lds + wv * 1024;
        #pragma unroll
        for (int it = 0; it < 16; ++it)
            GLDS(g + it * 8192, l + it * 8192);
        if (wv < 4)
            GLDS(ws + 131072 + wv * 1024 + lane * 16, lds + 131072 + wv * 1024);
    }

    // ---- both x tiles -> registers up-front (fully coalesced) ----
    float4 xv[2][4];
    {
        const float4* xg = (const float4*)(x + (size_t)row0 * 64);
        #pragma unroll
        for (int i = 0; i < 4; ++i) xv[0][i] = xg[tid + 512 * i];
        #pragma unroll
        for (int i = 0; i < 4; ++i) xv[1][i] = xg[2048 + tid + 512 * i];
    }
    // ---- W_x (3x64 fp32) -> LDS ----
    if (tid < 48) {
        const int k = tid >> 4, c = tid & 15;
        *((float4*)(lds + W_OFF) + tid) = *((const float4*)(W + k * 1088) + c);
    }
    // ---- convert x tile 0 -> LDS chunk layout ----
    #pragma unroll
    for (int i = 0; i < 4; ++i) {
        const int f = tid + 512 * i;
        const float4 v = xv[0][i];
        const int row = f >> 4, sg = f & 15;
        uint2 q; q.x = pk_rtne(v.x, v.y); q.y = pk_rtne(v.z, v.w);
        *(uint2*)(lds + XB_OFF + (row >> 4) * 2048 + (sg >> 1) * 256 +
                  (row & 15) * 16 + (sg & 1) * 8) = q;
    }

    __syncthreads();   // GLDS + x0 + W staged

    bf16x8 af[8][2];
    const char* cB = lds + wv * 16384 + quad * 256 + l15 * 16;
    const float* c2p = (const float*)(lds + C2_OFF) + wv * 128 + l15;

    #pragma unroll
    for (int t = 0; t < 2; ++t) {
        // ---- A fragments from LDS (contiguous stripes) ----
        #pragma unroll
        for (int rt = 0; rt < 8; ++rt) {
            const char* ab = lds + XB_OFF + rt * 2048 + l15 * 16;
            af[rt][0] = *(const bf16x8*)(ab + quad * 256);
            af[rt][1] = *(const bf16x8*)(ab + (4 + quad) * 256);
        }
        // ---- x2 + Wx dots from bf16 tile: thread = (row, quarter) ----
        {
            const int r = tid >> 2, qq = tid & 3;
            const char* xr = lds + XB_OFF + (r >> 4) * 2048 + (r & 15) * 16;
            const bf16x8 h0 = *(const bf16x8*)(xr + (qq * 2 + 0) * 256);
            const bf16x8 h1 = *(const bf16x8*)(xr + (qq * 2 + 1) * 256);
            const float* w0 = (const float*)(lds + W_OFF) + 0 * 64 + qq * 16;
            const float* w1 = (const float*)(lds + W_OFF) + 1 * 64 + qq * 16;
            const float* w2 = (const float*)(lds + W_OFF) + 2 * 64 + qq * 16;
            float s2 = 0.f, d0 = 0.f, d1 = 0.f, d2 = 0.f;
            #pragma unroll
            for (int e = 0; e < 8; ++e) {
                const float a = bf2f(h0[e]), b = bf2f(h1[e]);
                s2 = fmaf(a, a, s2); s2 = fmaf(b, b, s2);
                d0 = fmaf(a, w0[e], d0); d0 = fmaf(b, w0[8 + e], d0);
                d1 = fmaf(a, w1[e], d1); d1 = fmaf(b, w1[8 + e], d1);
                d2 = fmaf(a, w2[e], d2); d2 = fmaf(b, w2[8 + e], d2);
            }
            #pragma unroll
            for (int m = 1; m <= 2; m <<= 1) {
                s2 += __shfl_xor(s2, m);
                d0 += __shfl_xor(d0, m);
                d1 += __shfl_xor(d1, m);
                d2 += __shfl_xor(d2, m);
            }
            if (qq == 0) {
                ((float*)(lds + X2_OFF))[r] = s2;
                float* red = (float*)(lds + RED_OFF + t * 1536);
                red[r * 3 + 0] = d0 + bb0;
                red[r * 3 + 1] = d1 + bb1;
                red[r * 3 + 2] = d2 + bb2;
            }
        }
        __syncthreads();   // x2/red(t) seeded; XB(t) readers done after frag loads

        // next tile's x -> LDS (XB now dead for tile t: af are in registers)
        if (t == 0) {
            #pragma unroll
            for (int i = 0; i < 4; ++i) {
                const int f = tid + 512 * i;
                const float4 v = xv[1][i];
                const int row = f >> 4, sg = f & 15;
                uint2 q; q.x = pk_rtne(v.x, v.y); q.y = pk_rtne(v.z, v.w);
                *(uint2*)(lds + XB_OFF + (row >> 4) * 2048 + (sg >> 1) * 256 +
                          (row & 15) * 16 + (sg & 1) * 8) = q;
            }
        }

        // ---- prermax ----
        const float* px2 = (const float*)(lds + X2_OFF);
        float mn = 1e30f;
        #pragma unroll
        for (int rt = 0; rt < 8; ++rt) {
            const float4 q4 = *(const float4*)(px2 + rt * 16 + quad * 4);
            mn = fminf(mn, fminf(fminf(q4.x, q4.y), fminf(q4.z, q4.w)));
        }
        const float prermax = -BETA * mn;

        // ---- hot loop: 8 col-tiles, branch-free, 16 MFMA per B-pair ----
        float gm = -1e30f;
        #pragma unroll
        for (int ct = 0; ct < 8; ++ct) {
            const bf16x8 b0 = *(const bf16x8*)(cB + ct * 2048);
            const bf16x8 b1 = *(const bf16x8*)(cB + ct * 2048 + 1024);
            const float c2v = c2p[ct * 16];
            f32x4 acc[8];
            #pragma unroll
            for (int rt = 0; rt < 8; ++rt) {
                const f32x4 z = {0.f, 0.f, 0.f, 0.f};
                acc[rt] = __builtin_amdgcn_mfma_f32_16x16x32_bf16(af[rt][0], b0, z, 0, 0, 0);
                acc[rt] = __builtin_amdgcn_mfma_f32_16x16x32_bf16(af[rt][1], b1, acc[rt], 0, 0, 0);
            }
            f32x4 m0 = vmax4(vmax4(acc[0], acc[1]), vmax4(acc[2], acc[3]));
            f32x4 m1 = vmax4(vmax4(acc[4], acc[5]), vmax4(acc[6], acc[7]));
            m0 = vmax4(m0, m1);
            const float m = fmaxf(fmaxf(m0[0], m0[1]), fmaxf(m0[2], m0[3]));
            gm = fmaxf(gm, fmaf(2.0f * BETA, m, c2v));
        }
        const float bound = gm + prermax;

        // ---- cold exact path (statistically never) ----
        if (__builtin_expect(__ballot(bound > THRESH) != 0ull, 0)) {
            float* red = (float*)(lds + RED_OFF + t * 1536);
            #pragma clang loop unroll(disable)
            for (int ct = 0; ct < 8; ++ct) {
                const int j = wv * 128 + ct * 16 + l15;
                #pragma clang loop unroll(disable)
                for (int rr = 0; rr < 32; ++rr) {
                    const int r = (rr >> 2) * 16 + quad * 4 + (rr & 3);
                    const float* xr = x + (size_t)(row0 + t * 128 + r) * 64;
                    const float* cr = centers + (size_t)j * 64;
                    float d2 = 0.f;
                    #pragma clang loop unroll(disable)
                    for (int k = 0; k < 64; ++k) {
                        const float df = xr[k] - cr[k];
                        d2 = fmaf(df, df, d2);
                    }
                    const float arg = -BETA * d2;
                    if (arg > -87.f) {
                        const float e = expf(arg);
                        atomicAdd(&red[r * 3 + 0], e * W[0 * 1088 + 64 + j]);
                        atomicAdd(&red[r * 3 + 1], e * W[1 * 1088 + 64 + j]);
                        atomicAdd(&red[r * 3 + 2], e * W[2 * 1088 + 64 + j]);
                    }
                }
            }
        }
        __syncthreads();   // red(t) final; XB holds tile t+1

        // ---- coalesced store for this tile (other waves proceed) ----
        if (tid < 96)
            ((float4*)out)[blockIdx.x * 192 + t * 96 + tid] =
                *((const float4*)(lds + RED_OFF + t * 1536) + tid);
    }
}

extern "C" void kernel_launch(void* const* d_in, const int* in_sizes, int n_in,
                              void* d_out, int out_size, void* d_ws, size_t ws_size,
                              hipStream_t stream) {
    const float* x       = (const float*)d_in[0];
    const float* centers = (const float*)d_in[1];
    const float* W       = (const float*)d_in[2];
    const float* b       = (const float*)d_in[3];
    float* out = (float*)d_out;

    uint32* cbf = (uint32*)d_ws;                        // 128 KB bf16 chunks
    float*  c2m = (float*)((char*)d_ws + 131072);       // 4 KB -B*||c||^2

    const int n = in_sizes[0] / 64;                     // 65536 rows

    rbfn_prep<<<16, 256, 0, stream>>>(centers, cbf, c2m);
    rbfn_main<<<n / 256, 512, 0, stream>>>(x, (const char*)d_ws, W, b, centers, out);
}